// Round 1
// baseline (878.416 us; speedup 1.0000x reference)
//
#include <hip/hip_runtime.h>

#define D_H  1024
#define D_FF 4096
#define N_EXP 8
#define TOPK 2

typedef __attribute__((ext_vector_type(8))) __bf16 bf16x8;
typedef __attribute__((ext_vector_type(4))) float  f32x4;

__device__ __forceinline__ unsigned short f2bf(float f) {
    union { float f; unsigned int u; } a; a.f = f;
    return (unsigned short)((a.u + 0x7FFFu + ((a.u >> 16) & 1u)) >> 16);
}

#define GLOAD16(g, l) __builtin_amdgcn_global_load_lds( \
    (const __attribute__((address_space(1))) unsigned int*)(g), \
    (__attribute__((address_space(3))) unsigned int*)(l), 16, 0, 0)

// ---------------- fp32 -> bf16 convert (X) ----------------
__global__ void k_cvt_x(const float* __restrict__ x, unsigned short* __restrict__ xb, int n4) {
    int i = blockIdx.x * blockDim.x + threadIdx.x;
    if (i >= n4) return;
    float4 v = reinterpret_cast<const float4*>(x)[i];
    ushort4 o;
    o.x = f2bf(v.x); o.y = f2bf(v.y); o.z = f2bf(v.z); o.w = f2bf(v.w);
    reinterpret_cast<ushort4*>(xb)[i] = o;
}

// ---------------- transpose + convert: src [E][R][C] f32 -> dst [E][C][R] bf16 ----------------
__global__ void k_transpose(const float* __restrict__ src, unsigned short* __restrict__ dst,
                            int R, int C) {
    __shared__ float tile[32][33];
    int e = blockIdx.z;
    const float* S = src + (size_t)e * R * C;
    unsigned short* Dd = dst + (size_t)e * R * C;
    int c0 = blockIdx.x * 32, r0 = blockIdx.y * 32;
    int tx = threadIdx.x & 31, ty = threadIdx.x >> 5;
    #pragma unroll
    for (int i = 0; i < 32; i += 8)
        tile[ty + i][tx] = S[(size_t)(r0 + ty + i) * C + (c0 + tx)];
    __syncthreads();
    #pragma unroll
    for (int i = 0; i < 32; i += 8)
        Dd[(size_t)(c0 + ty + i) * R + (r0 + tx)] = f2bf(tile[tx][ty + i]);
}

// ---------------- routing: sigmoid gates, top-2, normalize, build expert lists ----------------
__global__ void k_route(const float* __restrict__ x, const float* __restrict__ cent, int N,
                        int* __restrict__ cnt, int* __restrict__ perm, float* __restrict__ wgt) {
    int gid = blockIdx.x * blockDim.x + threadIdx.x;
    int tok = gid >> 6;
    int lane = threadIdx.x & 63;
    if (tok >= N) return;
    const float4* xr = reinterpret_cast<const float4*>(x + (size_t)tok * D_H);
    const float4* cr = reinterpret_cast<const float4*>(cent);
    float acc[N_EXP];
    #pragma unroll
    for (int e = 0; e < N_EXP; ++e) acc[e] = 0.f;
    #pragma unroll
    for (int c = 0; c < 4; ++c) {
        float4 u = xr[lane + c * 64];
        #pragma unroll
        for (int e = 0; e < N_EXP; ++e) {
            float4 cv = cr[e * 256 + lane + c * 64];
            acc[e] += u.x * cv.x + u.y * cv.y + u.z * cv.z + u.w * cv.w;
        }
    }
    #pragma unroll
    for (int e = 0; e < N_EXP; ++e) {
        float v = acc[e];
        #pragma unroll
        for (int s = 32; s > 0; s >>= 1) v += __shfl_xor(v, s, 64);
        acc[e] = v;
    }
    if (lane == 0) {
        float g[N_EXP];
        #pragma unroll
        for (int e = 0; e < N_EXP; ++e) g[e] = 1.f / (1.f + expf(-acc[e]));
        int i1 = 0;
        #pragma unroll
        for (int e = 1; e < N_EXP; ++e) if (g[e] > g[i1]) i1 = e;   // lowest-index max (jax tie rule)
        int i2 = (i1 == 0) ? 1 : 0;
        #pragma unroll
        for (int e = 0; e < N_EXP; ++e) if (e != i1 && e != i2 && g[e] > g[i2]) i2 = e;
        float s = g[i1] + g[i2];
        int p1 = atomicAdd(&cnt[i1], 1);
        perm[i1 * N + p1] = tok; wgt[i1 * N + p1] = g[i1] / s;
        int p2 = atomicAdd(&cnt[i2], 1);
        perm[i2 * N + p2] = tok; wgt[i2 * N + p2] = g[i2] / s;
    }
}

// ---------------- tiny exclusive prefix sum over 8 counts ----------------
__global__ void k_offs(const int* __restrict__ cnt, int* __restrict__ offs) {
    if (threadIdx.x == 0 && blockIdx.x == 0) {
        int s = 0;
        for (int e = 0; e < N_EXP; ++e) { offs[e] = s; s += cnt[e]; }
    }
}

// ---------------- GEMM1: H[offs_e+p][:] = gelu(X[perm] @ W1[e] + b1[e]), bf16 out ----------------
__global__ __launch_bounds__(256) void k_gemm1(
    const unsigned short* __restrict__ Xb, const unsigned short* __restrict__ W1T,
    const float* __restrict__ b1, const int* __restrict__ cnt, const int* __restrict__ offs,
    const int* __restrict__ perm, unsigned short* __restrict__ H, int N)
{
    int e = blockIdx.z;
    int cnt_e = cnt[e];
    int row0 = blockIdx.y * 128;
    if (row0 >= cnt_e) return;
    int n0 = blockIdx.x * 128;
    int tid = threadIdx.x, lane = tid & 63, w = tid >> 6;
    int wm = w >> 1, wn = w & 1;
    __shared__ __align__(16) unsigned short As[128 * 64];
    __shared__ __align__(16) unsigned short Bs[128 * 64];
    int lrow = lane >> 3, lcol = (lane & 7) * 8;
    const unsigned short* aSrc[4];
    const unsigned short* bSrc[4];
    #pragma unroll
    for (int i = 0; i < 4; ++i) {
        int r = row0 + w * 32 + i * 8 + lrow;
        r = min(r, cnt_e - 1);
        aSrc[i] = Xb + (size_t)perm[e * N + r] * D_H + lcol;
        int nn = n0 + w * 32 + i * 8 + lrow;
        bSrc[i] = W1T + ((size_t)e * D_FF + nn) * D_H + lcol;
    }
    f32x4 acc[4][4];
    #pragma unroll
    for (int m = 0; m < 4; ++m)
        #pragma unroll
        for (int n = 0; n < 4; ++n) acc[m][n] = (f32x4){0.f, 0.f, 0.f, 0.f};

    for (int k0 = 0; k0 < D_H; k0 += 64) {
        #pragma unroll
        for (int i = 0; i < 4; ++i) {
            GLOAD16(aSrc[i] + k0, &As[(w * 32 + i * 8) * 64]);
            GLOAD16(bSrc[i] + k0, &Bs[(w * 32 + i * 8) * 64]);
        }
        __syncthreads();
        #pragma unroll
        for (int kk = 0; kk < 2; ++kk) {
            bf16x8 af[4], bfr[4];
            #pragma unroll
            for (int m = 0; m < 4; ++m)
                af[m] = *reinterpret_cast<const bf16x8*>(
                    &As[(wm * 64 + m * 16 + (lane & 15)) * 64 + kk * 32 + (lane >> 4) * 8]);
            #pragma unroll
            for (int n = 0; n < 4; ++n)
                bfr[n] = *reinterpret_cast<const bf16x8*>(
                    &Bs[(wn * 64 + n * 16 + (lane & 15)) * 64 + kk * 32 + (lane >> 4) * 8]);
            #pragma unroll
            for (int m = 0; m < 4; ++m)
                #pragma unroll
                for (int n = 0; n < 4; ++n)
                    acc[m][n] = __builtin_amdgcn_mfma_f32_16x16x32_bf16(af[m], bfr[n], acc[m][n], 0, 0, 0);
        }
        __syncthreads();
    }
    int offs_e = offs[e];
    int rbase = 4 * (lane >> 4), ccol = lane & 15;
    #pragma unroll
    for (int n = 0; n < 4; ++n) {
        int gcol = n0 + wn * 64 + n * 16 + ccol;
        float bias = b1[e * D_FF + gcol];
        #pragma unroll
        for (int m = 0; m < 4; ++m) {
            #pragma unroll
            for (int j = 0; j < 4; ++j) {
                int p = row0 + wm * 64 + m * 16 + rbase + j;
                if (p < cnt_e) {
                    float v = acc[m][n][j] + bias;
                    v = 0.5f * v * (1.f + erff(v * 0.70710678118f));   // exact gelu
                    H[(size_t)(offs_e + p) * D_FF + gcol] = f2bf(v);
                }
            }
        }
    }
}

// ---------------- GEMM2: out[tok] += w * (H @ W2[e] + b2[e]) ----------------
__global__ __launch_bounds__(256) void k_gemm2(
    const unsigned short* __restrict__ H, const unsigned short* __restrict__ W2T,
    const float* __restrict__ b2, const int* __restrict__ cnt, const int* __restrict__ offs,
    const int* __restrict__ perm, const float* __restrict__ wgt,
    float* __restrict__ out, int N)
{
    int e = blockIdx.z;
    int cnt_e = cnt[e];
    int row0 = blockIdx.y * 128;
    if (row0 >= cnt_e) return;
    int n0 = blockIdx.x * 128;
    int tid = threadIdx.x, lane = tid & 63, w = tid >> 6;
    int wm = w >> 1, wn = w & 1;
    __shared__ __align__(16) unsigned short As[128 * 64];
    __shared__ __align__(16) unsigned short Bs[128 * 64];
    int lrow = lane >> 3, lcol = (lane & 7) * 8;
    int offs_e = offs[e];
    const unsigned short* aSrc[4];
    const unsigned short* bSrc[4];
    #pragma unroll
    for (int i = 0; i < 4; ++i) {
        int r = row0 + w * 32 + i * 8 + lrow;
        r = min(r, cnt_e - 1);
        aSrc[i] = H + (size_t)(offs_e + r) * D_FF + lcol;
        int nn = n0 + w * 32 + i * 8 + lrow;
        bSrc[i] = W2T + ((size_t)e * D_H + nn) * D_FF + lcol;
    }
    f32x4 acc[4][4];
    #pragma unroll
    for (int m = 0; m < 4; ++m)
        #pragma unroll
        for (int n = 0; n < 4; ++n) acc[m][n] = (f32x4){0.f, 0.f, 0.f, 0.f};

    for (int k0 = 0; k0 < D_FF; k0 += 64) {
        #pragma unroll
        for (int i = 0; i < 4; ++i) {
            GLOAD16(aSrc[i] + k0, &As[(w * 32 + i * 8) * 64]);
            GLOAD16(bSrc[i] + k0, &Bs[(w * 32 + i * 8) * 64]);
        }
        __syncthreads();
        #pragma unroll
        for (int kk = 0; kk < 2; ++kk) {
            bf16x8 af[4], bfr[4];
            #pragma unroll
            for (int m = 0; m < 4; ++m)
                af[m] = *reinterpret_cast<const bf16x8*>(
                    &As[(wm * 64 + m * 16 + (lane & 15)) * 64 + kk * 32 + (lane >> 4) * 8]);
            #pragma unroll
            for (int n = 0; n < 4; ++n)
                bfr[n] = *reinterpret_cast<const bf16x8*>(
                    &Bs[(wn * 64 + n * 16 + (lane & 15)) * 64 + kk * 32 + (lane >> 4) * 8]);
            #pragma unroll
            for (int m = 0; m < 4; ++m)
                #pragma unroll
                for (int n = 0; n < 4; ++n)
                    acc[m][n] = __builtin_amdgcn_mfma_f32_16x16x32_bf16(af[m], bfr[n], acc[m][n], 0, 0, 0);
        }
        __syncthreads();
    }
    int rbase = 4 * (lane >> 4), ccol = lane & 15;
    #pragma unroll
    for (int n = 0; n < 4; ++n) {
        int gcol = n0 + wn * 64 + n * 16 + ccol;
        float bias = b2[e * D_H + gcol];
        #pragma unroll
        for (int m = 0; m < 4; ++m) {
            #pragma unroll
            for (int j = 0; j < 4; ++j) {
                int p = row0 + wm * 64 + m * 16 + rbase + j;
                if (p < cnt_e) {
                    int tok = perm[e * N + p];
                    float wv = wgt[e * N + p];
                    atomicAdd(&out[(size_t)tok * D_H + gcol], wv * (acc[m][n][j] + bias));
                }
            }
        }
    }
}

extern "C" void kernel_launch(void* const* d_in, const int* in_sizes, int n_in,
                              void* d_out, int out_size, void* d_ws, size_t ws_size,
                              hipStream_t stream) {
    (void)n_in; (void)ws_size;
    const float* x    = (const float*)d_in[0];
    const float* cent = (const float*)d_in[1];
    const float* W1   = (const float*)d_in[2];
    const float* b1   = (const float*)d_in[3];
    const float* W2   = (const float*)d_in[4];
    const float* b2   = (const float*)d_in[5];
    float* out = (float*)d_out;
    int N = in_sizes[0] / D_H;   // 4096 tokens

    char* ws = (char*)d_ws;
    size_t off = 0;
    auto carve = [&](size_t bytes) -> char* {
        char* p = ws + off;
        off += (bytes + 255) & ~(size_t)255;
        return p;
    };
    unsigned short* Xb   = (unsigned short*)carve((size_t)N * D_H * 2);
    unsigned short* W1T  = (unsigned short*)carve((size_t)N_EXP * D_FF * D_H * 2);
    unsigned short* W2T  = (unsigned short*)carve((size_t)N_EXP * D_H * D_FF * 2);
    unsigned short* H    = (unsigned short*)carve((size_t)N * TOPK * D_FF * 2);
    int*            perm = (int*)carve((size_t)N_EXP * N * 4);
    float*          wgt  = (float*)carve((size_t)N_EXP * N * 4);
    int*            cnt  = (int*)carve(64);
    int*            offs = (int*)carve(64);

    hipMemsetAsync(cnt, 0, 64, stream);
    hipMemsetAsync(out, 0, (size_t)out_size * sizeof(float), stream);

    k_cvt_x<<<dim3((N * D_H / 4 + 255) / 256), 256, 0, stream>>>(x, Xb, N * D_H / 4);
    k_transpose<<<dim3(D_FF / 32, D_H / 32, N_EXP), 256, 0, stream>>>(W1, W1T, D_H, D_FF);
    k_transpose<<<dim3(D_H / 32, D_FF / 32, N_EXP), 256, 0, stream>>>(W2, W2T, D_FF, D_H);
    k_route<<<dim3(N / 4), 256, 0, stream>>>(x, cent, N, cnt, perm, wgt);
    k_offs<<<1, 64, 0, stream>>>(cnt, offs);
    k_gemm1<<<dim3(D_FF / 128, (N + 127) / 128, N_EXP), 256, 0, stream>>>(Xb, W1T, b1, cnt, offs, perm, H, N);
    k_gemm2<<<dim3(D_H / 128, (N + 127) / 128, N_EXP), 256, 0, stream>>>(H, W2T, b2, cnt, offs, perm, wgt, out, N);
}